// Round 2
// baseline (242.004 us; speedup 1.0000x reference)
//
#include <hip/hip_runtime.h>
#include <hip/hip_bf16.h>
#include <hip/hip_cooperative_groups.h>

namespace cg = cooperative_groups;

// DisenGCN forward, fully fused cooperative kernel.
// Sides: 0 = user (eu), 1 = item (ei). n_rows = n_neigh + 1 (4097).
// Geometry: d_in=64, K=4 channels, d_out=16, flat=64. lane m = k*16+d.
//
// ws layout (floats):
//   z   : 2 * n_rows * 64   raw relu(proj) rows per side
//   zn  : 2 * n_rows * 64   row-normalized (per 16-lane channel) copies
//   acc : 12 * 64           routed row-0, slot(L,t,side) = ((L*3+t)*2+side)*64

#define NW   16      // waves per block (blockDim = 1024)
#define GBLK 256     // blocks (1 per CU)

__device__ __forceinline__ float grp16_sum(float v) {
    v += __shfl_xor(v, 1, 64);
    v += __shfl_xor(v, 2, 64);
    v += __shfl_xor(v, 4, 64);
    v += __shfl_xor(v, 8, 64);
    return v;  // sum within each 16-lane group (channel k)
}

// relu(b[k][d] + sum_i x[i]*W[k][i][d]) for lane m=k*16+d; x lives one elem/lane.
__device__ __forceinline__ float proj_row(float x, const float* __restrict__ W,
                                          const float* __restrict__ b, int lane) {
    const int k = lane >> 4, d = lane & 15;
    float sum = b[k * 16 + d];
    const float* __restrict__ Wp = W + k * 1024 + d;  // W[k][i][d], stride 16 over i
#pragma unroll
    for (int i = 0; i < 64; ++i)
        sum = fmaf(__shfl(x, i, 64), Wp[i * 16], sum);
    return fmaxf(sum, 0.f);
}

// One neighbor row's softmax-weighted contribution p[k]*zn[k][d].
__device__ __forceinline__ float route_contrib(float znv, float egon, int lane) {
    float dp = grp16_sum(znv * egon);  // per-channel dot, uniform in 16-lane group
    float d0 = __shfl(dp, 0, 64),  d1 = __shfl(dp, 16, 64);
    float d2 = __shfl(dp, 32, 64), d3 = __shfl(dp, 48, 64);
    float mx = fmaxf(fmaxf(d0, d1), fmaxf(d2, d3));
    float den = expf(d0 - mx) + expf(d1 - mx) + expf(d2 - mx) + expf(d3 - mx);
    float pk = expf(dp - mx) / den;
    return pk * znv;
}

__global__ __launch_bounds__(1024, 1) void disen_fused(
    const int* __restrict__ user, const int* __restrict__ item,
    const int* __restrict__ nu, const int* __restrict__ ni,
    const float* __restrict__ Gu, const float* __restrict__ Gi,
    const float* __restrict__ W0, const float* __restrict__ b0,
    const float* __restrict__ W1, const float* __restrict__ b1,
    float* __restrict__ z, float* __restrict__ zn, float* __restrict__ acc,
    float* __restrict__ out, int n_neigh)
{
    const int n_rows = n_neigh + 1;
    const int lane = threadIdx.x & 63;
    const int wv   = threadIdx.x >> 6;
    const int side = blockIdx.x & 1;           // even blocks: user, odd: item
    const int bg   = blockIdx.x >> 1;          // block index within side
    const int nbg  = gridDim.x >> 1;
    float* __restrict__ zs  = z  + (size_t)side * n_rows * 64;
    float* __restrict__ zns = zn + (size_t)side * n_rows * 64;

    cg::grid_group grid = cg::this_grid();
    __shared__ float red[NW][64];

    // ---- zero acc slots (block 0) ----
    if (blockIdx.x == 0)
        for (int i = threadIdx.x; i < 12 * 64; i += blockDim.x) acc[i] = 0.f;

    // ---- P0: layer-0 projection + per-channel normalize ----
    for (int n = bg * NW + wv; n < n_rows; n += nbg * NW) {
        float x;
        if (n == 0)
            x = side ? Gi[(size_t)item[0] * 64 + lane]
                     : Gu[(size_t)user[0] * 64 + lane];
        else
            x = side ? Gu[(size_t)ni[n - 1] * 64 + lane]
                     : Gi[(size_t)nu[n - 1] * 64 + lane];
        float zv = proj_row(x, W0, b0, lane);
        zs[(size_t)n * 64 + lane] = zv;
        float nrm = fmaxf(sqrtf(grp16_sum(zv * zv)), 1e-12f);
        zns[(size_t)n * 64 + lane] = zv / nrm;
    }
    grid.sync();

    // ---- layers: route x3 (L0), proj L1, route x3 (L1) ----
    for (int L = 0; L < 2; ++L) {
        for (int t = 0; t < 3; ++t) {
            const int slot = (L * 3 + t) * 2 + side;
            float e;
            if (t == 0) {
                e = zns[lane];                               // normalized row 0
            } else {
                float ep = acc[((L * 3 + t - 1) * 2 + side) * 64 + lane];
                e = ep / fmaxf(sqrtf(grp16_sum(ep * ep)), 1e-12f);
            }
            float accL = 0.f;
            for (int n = 1 + bg * NW + wv; n <= n_neigh; n += nbg * NW)
                accL += route_contrib(zns[(size_t)n * 64 + lane], e, lane);
            red[wv][lane] = accL;
            __syncthreads();
            if (wv == 0) {
                float s = 0.f;
#pragma unroll
                for (int j = 0; j < NW; ++j) s += red[j][lane];
                atomicAdd(&acc[slot * 64 + lane], s);
            }
            grid.sync();  // acc[slot] complete; also guards red[] reuse
        }
        if (L == 0) {
            // ---- P2: layer-1 projection (in place), row 0 from routed L0 t2 ----
            for (int n = bg * NW + wv; n < n_rows; n += nbg * NW) {
                float x = (n == 0) ? acc[(2 * 2 + side) * 64 + lane]
                                   : zs[(size_t)n * 64 + lane];
                float zv = proj_row(x, W1, b1, lane);
                zs[(size_t)n * 64 + lane] = zv;
                float nrm = fmaxf(sqrtf(grp16_sum(zv * zv)), 1e-12f);
                zns[(size_t)n * 64 + lane] = zv / nrm;
            }
            grid.sync();
        }
    }

    // ---- final: xui, eu0, ei0 ----
    if (blockIdx.x == 0 && wv == 0) {
        float u = acc[(5 * 2 + 0) * 64 + lane];  // L1 t2 user
        float v = acc[(5 * 2 + 1) * 64 + lane];  // L1 t2 item
        out[1 + lane]  = u;
        out[65 + lane] = v;
        float p = u * v;
#pragma unroll
        for (int s = 32; s >= 1; s >>= 1) p += __shfl_xor(p, s, 64);
        if (lane == 0) out[0] = p;
    }
}

extern "C" void kernel_launch(void* const* d_in, const int* in_sizes, int n_in,
                              void* d_out, int out_size, void* d_ws, size_t ws_size,
                              hipStream_t stream) {
    const int*   user       = (const int*)d_in[0];
    const int*   item       = (const int*)d_in[1];
    const int*   neigh_user = (const int*)d_in[2];
    const int*   neigh_item = (const int*)d_in[3];
    const float* Gu         = (const float*)d_in[4];
    const float* Gi         = (const float*)d_in[5];
    const float* W0         = (const float*)d_in[6];
    const float* b0         = (const float*)d_in[7];
    const float* W1         = (const float*)d_in[8];
    const float* b1         = (const float*)d_in[9];
    float* out = (float*)d_out;

    int n_neigh = in_sizes[2];
    int n_rows  = n_neigh + 1;

    float* z   = (float*)d_ws;
    float* zn  = z  + (size_t)2 * n_rows * 64;
    float* acc = zn + (size_t)2 * n_rows * 64;

    void* args[] = {
        (void*)&user, (void*)&item, (void*)&neigh_user, (void*)&neigh_item,
        (void*)&Gu, (void*)&Gi, (void*)&W0, (void*)&b0, (void*)&W1, (void*)&b1,
        (void*)&z, (void*)&zn, (void*)&acc, (void*)&out, (void*)&n_neigh
    };
    hipLaunchCooperativeKernel((const void*)disen_fused,
                               dim3(GBLK), dim3(1024), args, 0, stream);
}

// Round 3
// 206.941 us; speedup vs baseline: 1.1694x; 1.1694x over previous
//
#include <hip/hip_runtime.h>
#include <hip/hip_bf16.h>

// DisenGCN forward — 8-dispatch graph chain.
// Sides: 0 = user, 1 = item. n_rows = n_neigh + 1 (4097).
// Geometry: d_in=64, K=4, d_out=16, flat=64. lane m = k*16+d.
//
// ws layout (floats):
//   z   : 2*n_rows*64   relu(proj) rows per side
//   zn  : 2*n_rows*64   per-channel-normalized rows
//   acc : 12*64         routed row-0, slot s=(L*3+t), addr (s*2+side)*64
//   ticket : 1 int      last-block election for fused finalize

#define RPW 4            // rows per wave in proj
#define PROJ_WAVES 4     // waves per proj block (block = 256)
#define ROUTE_BLOCKS 128 // per side; block = 256 (4 waves)

__device__ __forceinline__ float grp16_sum(float v) {
    v += __shfl_xor(v, 1, 64);
    v += __shfl_xor(v, 2, 64);
    v += __shfl_xor(v, 4, 64);
    v += __shfl_xor(v, 8, 64);
    return v;  // sum within each 16-lane group (channel)
}

// Projection: 4 rows per wave, layer select via `layer`.
// Also zeroes acc/ticket when layer==0 (block (0,0)).
__global__ void proj_kernel(
    const int* __restrict__ user, const int* __restrict__ item,
    const int* __restrict__ nu, const int* __restrict__ ni,
    const float* __restrict__ Gu, const float* __restrict__ Gi,
    const float* __restrict__ W, const float* __restrict__ b,
    float* __restrict__ z, float* __restrict__ zn,
    float* __restrict__ acc, int* __restrict__ ticket,
    int layer, int n_rows)
{
    if (layer == 0 && blockIdx.x == 0 && blockIdx.y == 0) {
        for (int i = threadIdx.x; i < 12 * 64; i += blockDim.x) acc[i] = 0.f;
        if (threadIdx.x == 0) *ticket = 0;
    }

    const int lane = threadIdx.x & 63;
    const int wv   = threadIdx.x >> 6;
    const int side = blockIdx.y;
    float* __restrict__ zs  = z  + (size_t)side * n_rows * 64;
    float* __restrict__ zns = zn + (size_t)side * n_rows * 64;

    const int n0 = (blockIdx.x * PROJ_WAVES + wv) * RPW;
    if (n0 >= n_rows) return;

    float x[RPW];
#pragma unroll
    for (int r = 0; r < RPW; ++r) {
        const int n = n0 + r;
        if (n >= n_rows) { x[r] = 0.f; continue; }
        if (layer == 0) {
            if (n == 0)
                x[r] = side ? Gi[(size_t)item[0] * 64 + lane]
                            : Gu[(size_t)user[0] * 64 + lane];
            else
                x[r] = side ? Gu[(size_t)ni[n - 1] * 64 + lane]
                            : Gi[(size_t)nu[n - 1] * 64 + lane];
        } else {
            // layer 1: row 0 input = routed L0 t2 (slot s=2), raw
            x[r] = (n == 0) ? acc[(2 * 2 + side) * 64 + lane]
                            : zs[(size_t)n * 64 + lane];
        }
    }

    const int k = lane >> 4, d = lane & 15;
    float sum[RPW];
#pragma unroll
    for (int r = 0; r < RPW; ++r) sum[r] = b[k * 16 + d];
    const float* __restrict__ Wp = W + k * 1024 + d;  // W[k][i][d], stride 16 over i
#pragma unroll
    for (int i = 0; i < 64; ++i) {
        const float w = Wp[i * 16];
#pragma unroll
        for (int r = 0; r < RPW; ++r)
            sum[r] = fmaf(__shfl(x[r], i, 64), w, sum[r]);
    }

#pragma unroll
    for (int r = 0; r < RPW; ++r) {
        const int n = n0 + r;
        if (n >= n_rows) break;
        const float zv = fmaxf(sum[r], 0.f);
        zs[(size_t)n * 64 + lane] = zv;
        const float nrm = fmaxf(sqrtf(grp16_sum(zv * zv)), 1e-12f);
        zns[(size_t)n * 64 + lane] = zv / nrm;
    }
}

// One routing iteration (both sides via blockIdx.y). Reads precomputed zn.
// use_row0: ego = zn row 0; else ego = normalize(acc[prev_s]).
// Last route (is_last) elects the final block via ticket and fuses finalize.
__global__ void route_kernel(
    const float* __restrict__ zn, const float* __restrict__ acc_ro,
    float* __restrict__ acc, int* __restrict__ ticket, float* __restrict__ out,
    int use_row0, int prev_s, int cur_s, int is_last, int n_neigh)
{
    const int n_rows = n_neigh + 1;
    const int lane = threadIdx.x & 63;
    const int wv   = threadIdx.x >> 6;
    const int side = blockIdx.y;
    const float* __restrict__ zns = zn + (size_t)side * n_rows * 64;

    float e = use_row0 ? zns[lane] : acc_ro[(prev_s * 2 + side) * 64 + lane];
    const float egon = e / fmaxf(sqrtf(grp16_sum(e * e)), 1e-12f);

    float accL = 0.f;
    const int nwv = gridDim.x * (blockDim.x >> 6);
    const int wid = blockIdx.x * (blockDim.x >> 6) + wv;
    for (int n = 1 + wid; n <= n_neigh; n += nwv) {
        const float znv = zns[(size_t)n * 64 + lane];
        const float dp = grp16_sum(znv * egon);  // per-channel dot
        const float d0 = __shfl(dp, 0, 64),  d1 = __shfl(dp, 16, 64);
        const float d2 = __shfl(dp, 32, 64), d3 = __shfl(dp, 48, 64);
        const float mx = fmaxf(fmaxf(d0, d1), fmaxf(d2, d3));
        const float den = expf(d0 - mx) + expf(d1 - mx) + expf(d2 - mx) + expf(d3 - mx);
        accL = fmaf(expf(dp - mx) / den, znv, accL);
    }

    __shared__ float red[4][64];
    red[wv][lane] = accL;
    __syncthreads();
    if (wv == 0) {
        float s = red[0][lane] + red[1][lane] + red[2][lane] + red[3][lane];
        atomicAdd(&acc[(cur_s * 2 + side) * 64 + lane], s);
    }

    if (is_last) {
        __threadfence();
        __shared__ int tk;
        if (threadIdx.x == 0) tk = atomicAdd(ticket, 1);
        __syncthreads();
        if (tk == (int)(gridDim.x * 2) - 1 && wv == 0) {
            __threadfence();
            // device-scope atomic reads: safe across XCD L2s
            const float u = atomicAdd(&acc[(5 * 2 + 0) * 64 + lane], 0.f);
            const float v = atomicAdd(&acc[(5 * 2 + 1) * 64 + lane], 0.f);
            out[1 + lane]  = u;
            out[65 + lane] = v;
            float p = u * v;
#pragma unroll
            for (int s = 32; s >= 1; s >>= 1) p += __shfl_xor(p, s, 64);
            if (lane == 0) out[0] = p;
        }
    }
}

extern "C" void kernel_launch(void* const* d_in, const int* in_sizes, int n_in,
                              void* d_out, int out_size, void* d_ws, size_t ws_size,
                              hipStream_t stream) {
    const int*   user       = (const int*)d_in[0];
    const int*   item       = (const int*)d_in[1];
    const int*   neigh_user = (const int*)d_in[2];
    const int*   neigh_item = (const int*)d_in[3];
    const float* Gu         = (const float*)d_in[4];
    const float* Gi         = (const float*)d_in[5];
    const float* W0         = (const float*)d_in[6];
    const float* b0         = (const float*)d_in[7];
    const float* W1         = (const float*)d_in[8];
    const float* b1         = (const float*)d_in[9];
    float* out = (float*)d_out;

    const int n_neigh = in_sizes[2];
    const int n_rows  = n_neigh + 1;

    float* z      = (float*)d_ws;
    float* zn     = z  + (size_t)2 * n_rows * 64;
    float* acc    = zn + (size_t)2 * n_rows * 64;
    int*   ticket = (int*)(acc + 12 * 64);

    const dim3 pgrid((n_rows + PROJ_WAVES * RPW - 1) / (PROJ_WAVES * RPW), 2);
    const dim3 pblock(64 * PROJ_WAVES);
    const dim3 rgrid(ROUTE_BLOCKS, 2);
    const dim3 rblock(256);

    // layer 0
    hipLaunchKernelGGL(proj_kernel, pgrid, pblock, 0, stream,
                       user, item, neigh_user, neigh_item, Gu, Gi, W0, b0,
                       z, zn, acc, ticket, 0, n_rows);
    hipLaunchKernelGGL(route_kernel, rgrid, rblock, 0, stream,
                       zn, acc, acc, ticket, out, 1, 0, 0, 0, n_neigh);
    hipLaunchKernelGGL(route_kernel, rgrid, rblock, 0, stream,
                       zn, acc, acc, ticket, out, 0, 0, 1, 0, n_neigh);
    hipLaunchKernelGGL(route_kernel, rgrid, rblock, 0, stream,
                       zn, acc, acc, ticket, out, 0, 1, 2, 0, n_neigh);
    // layer 1
    hipLaunchKernelGGL(proj_kernel, pgrid, pblock, 0, stream,
                       user, item, neigh_user, neigh_item, Gu, Gi, W1, b1,
                       z, zn, acc, ticket, 1, n_rows);
    hipLaunchKernelGGL(route_kernel, rgrid, rblock, 0, stream,
                       zn, acc, acc, ticket, out, 1, 0, 3, 0, n_neigh);
    hipLaunchKernelGGL(route_kernel, rgrid, rblock, 0, stream,
                       zn, acc, acc, ticket, out, 0, 3, 4, 0, n_neigh);
    hipLaunchKernelGGL(route_kernel, rgrid, rblock, 0, stream,
                       zn, acc, acc, ticket, out, 0, 4, 5, 1, n_neigh);
}

// Round 4
// 127.443 us; speedup vs baseline: 1.8989x; 1.6238x over previous
//
#include <hip/hip_runtime.h>
#include <hip/hip_bf16.h>

// DisenGCN forward — 9-dispatch chain: gather | proj | 3x route | proj | 3x route.
// Sides: 0=user, 1=item. n_rows = n_neigh+1 (4097). Row = 64 f32 = 16 float4.
// Row layout per 64-lane wave (routes/gather): lanes [16g..16g+15] = row group g,
// lane chunk c = lane&15 holds float4 elems [4c..4c+3]; channel k = c>>2.
//
// ws layout (floats):
//   eg  : 2*n_rows*64   gathered input rows (contiguous, side-major)
//   z   : 2*n_rows*64   relu(proj)
//   zn  : 2*n_rows*64   per-channel normalized
//   acc : 12*64         routed row-0, slot s=L*3+t, addr (s*2+side)*64
//   ticket : 1 int

#define ROUTE_BLOCKS 128  // per side, 256 thr = 4 waves => 512 waves/side

__device__ __forceinline__ float g4sum(float v) {
    v += __shfl_xor(v, 1, 64);
    v += __shfl_xor(v, 2, 64);
    return v;  // sum within 4-lane subgroup (one channel chunk-group)
}
__device__ __forceinline__ float g16sum(float v) {
    v += __shfl_xor(v, 1, 64);
    v += __shfl_xor(v, 2, 64);
    v += __shfl_xor(v, 4, 64);
    v += __shfl_xor(v, 8, 64);
    return v;  // sum within 16-lane group
}

// ---- Stage 0: pure random-row gather into contiguous eg; zero acc/ticket ----
__global__ void gather_kernel(
    const int* __restrict__ user, const int* __restrict__ item,
    const int* __restrict__ nu, const int* __restrict__ ni,
    const float* __restrict__ Gu, const float* __restrict__ Gi,
    float4* __restrict__ eg, float* __restrict__ acc, int* __restrict__ ticket,
    int n_rows)
{
    if (blockIdx.x == 0) {
        for (int i = threadIdx.x; i < 12 * 64; i += blockDim.x) acc[i] = 0.f;
        if (threadIdx.x == 0) *ticket = 0;
    }
    const int lane = threadIdx.x & 63;
    const int wv   = threadIdx.x >> 6;
    const int g    = lane >> 4;
    const int c    = lane & 15;
    const long r = ((long)blockIdx.x * 4 + wv) * 4 + g;  // combined row id
    if (r >= 2L * n_rows) return;
    const int side = (r >= n_rows);
    const int n = side ? (int)(r - n_rows) : (int)r;
    int idx; const float* src;
    if (n == 0) { idx = side ? item[0] : user[0]; src = side ? Gi : Gu; }
    else        { idx = side ? ni[n - 1] : nu[n - 1]; src = side ? Gu : Gi; }
    eg[r * 16 + c] = ((const float4*)(src + (size_t)idx * 64))[c];
}

// ---- Projection: 1 row per wave. layer 0 reads eg; layer 1 reads z (row0: acc). ----
__global__ void proj_kernel(
    const float* __restrict__ W, const float* __restrict__ b,
    const float* __restrict__ eg, float* __restrict__ z, float* __restrict__ zn,
    const float* __restrict__ acc, int layer, int n_rows)
{
    const int lane = threadIdx.x & 63;
    const int wv   = threadIdx.x >> 6;
    const int side = blockIdx.y;
    const int n = blockIdx.x * 4 + wv;
    if (n >= n_rows) return;
    const size_t row = (size_t)side * n_rows + n;

    const float4* src4;
    if (layer == 0)           src4 = (const float4*)(eg + row * 64);
    else if (n == 0)          src4 = (const float4*)(acc + (2 * 2 + side) * 64);
    else                      src4 = (const float4*)(z + row * 64);
    const float4 xv = src4[lane & 15];
    const float xa[4] = {xv.x, xv.y, xv.z, xv.w};

    const int k = lane >> 4, d = lane & 15;
    float sum = b[k * 16 + d];
    const float* __restrict__ Wp = W + k * 1024 + d;  // W[k][i][d], stride 16 floats
#pragma unroll
    for (int i = 0; i < 64; ++i) {
        const float xi = __shfl(xa[i & 3], i >> 2, 64);
        sum = fmaf(xi, Wp[i * 16], sum);
    }
    const float zv = fmaxf(sum, 0.f);
    z[row * 64 + lane] = zv;
    const float nrm = fmaxf(sqrtf(g16sum(zv * zv)), 1e-12f);
    zn[row * 64 + lane] = zv / nrm;
}

// ---- Routing iteration: 4 rows/wave via float4. Last one fuses finalize. ----
__global__ void route_kernel(
    const float* __restrict__ zn, const float* __restrict__ acc_ro,
    float* __restrict__ acc, int* __restrict__ ticket, float* __restrict__ out,
    int use_row0, int prev_s, int cur_s, int is_last, int n_neigh)
{
    const int n_rows = n_neigh + 1;
    const int lane = threadIdx.x & 63;
    const int wv   = threadIdx.x >> 6;
    const int side = blockIdx.y;
    const int g    = lane >> 4;   // row subgroup
    const int c    = lane & 15;   // float4 chunk
    const int k    = c >> 2;      // channel
    const float4* __restrict__ zn4 = (const float4*)(zn + (size_t)side * n_rows * 64);

    // ego chunk c, per-channel normalized
    float4 e4;
    if (use_row0) e4 = zn4[c];
    else          e4 = ((const float4*)(acc_ro + (prev_s * 2 + side) * 64))[c];
    {
        const float ss = g4sum(e4.x * e4.x + e4.y * e4.y + e4.z * e4.z + e4.w * e4.w);
        const float inv = 1.f / fmaxf(sqrtf(ss), 1e-12f);
        e4.x *= inv; e4.y *= inv; e4.z *= inv; e4.w *= inv;
    }

    float4 a4 = {0.f, 0.f, 0.f, 0.f};
    const int nwv = gridDim.x * 4;               // waves per side
    const int wid = blockIdx.x * 4 + wv;
    for (int base = wid; ; base += nwv) {
        const int n = 1 + base * 4 + g;
        if (n > n_neigh) break;
        const float4 z4 = zn4[(size_t)n * 16 + c];
        float dp = g4sum(z4.x * e4.x + z4.y * e4.y + z4.z * e4.z + z4.w * e4.w);
        const int bl = lane & 48;
        const float d0 = __shfl(dp, bl, 64),      d1 = __shfl(dp, bl + 4, 64);
        const float d2 = __shfl(dp, bl + 8, 64),  d3 = __shfl(dp, bl + 12, 64);
        const float mx = fmaxf(fmaxf(d0, d1), fmaxf(d2, d3));
        const float e0 = expf(d0 - mx), e1 = expf(d1 - mx);
        const float e2 = expf(d2 - mx), e3 = expf(d3 - mx);
        const float den = e0 + e1 + e2 + e3;
        const float eo = (k == 0) ? e0 : (k == 1) ? e1 : (k == 2) ? e2 : e3;
        const float pk = eo / den;
        a4.x = fmaf(pk, z4.x, a4.x); a4.y = fmaf(pk, z4.y, a4.y);
        a4.z = fmaf(pk, z4.z, a4.z); a4.w = fmaf(pk, z4.w, a4.w);
    }

    __shared__ float4 red[4][64];
    red[wv][lane] = a4;
    __syncthreads();
    if (wv == 0) {
        float4 s = red[0][lane];
        const float4 s1 = red[1][lane], s2 = red[2][lane], s3 = red[3][lane];
        s.x += s1.x + s2.x + s3.x; s.y += s1.y + s2.y + s3.y;
        s.z += s1.z + s2.z + s3.z; s.w += s1.w + s2.w + s3.w;
        // sum the 4 row-subgroups (lanes l, l^16, l^32, l^48)
#pragma unroll
        for (int m = 16; m <= 32; m <<= 1) {
            s.x += __shfl_xor(s.x, m, 64); s.y += __shfl_xor(s.y, m, 64);
            s.z += __shfl_xor(s.z, m, 64); s.w += __shfl_xor(s.w, m, 64);
        }
        if (lane < 16) {
            float* dst = acc + (cur_s * 2 + side) * 64 + lane * 4;
            atomicAdd(dst + 0, s.x); atomicAdd(dst + 1, s.y);
            atomicAdd(dst + 2, s.z); atomicAdd(dst + 3, s.w);
        }
    }

    if (is_last) {
        __threadfence();
        __shared__ int tk;
        if (threadIdx.x == 0) tk = atomicAdd(ticket, 1);
        __syncthreads();
        if (tk == (int)(gridDim.x * 2) - 1 && wv == 0) {
            __threadfence();
            const float u = atomicAdd(&acc[(5 * 2 + 0) * 64 + lane], 0.f);
            const float v = atomicAdd(&acc[(5 * 2 + 1) * 64 + lane], 0.f);
            out[1 + lane]  = u;
            out[65 + lane] = v;
            float p = u * v;
#pragma unroll
            for (int s = 32; s >= 1; s >>= 1) p += __shfl_xor(p, s, 64);
            if (lane == 0) out[0] = p;
        }
    }
}

extern "C" void kernel_launch(void* const* d_in, const int* in_sizes, int n_in,
                              void* d_out, int out_size, void* d_ws, size_t ws_size,
                              hipStream_t stream) {
    const int*   user       = (const int*)d_in[0];
    const int*   item       = (const int*)d_in[1];
    const int*   neigh_user = (const int*)d_in[2];
    const int*   neigh_item = (const int*)d_in[3];
    const float* Gu         = (const float*)d_in[4];
    const float* Gi         = (const float*)d_in[5];
    const float* W0         = (const float*)d_in[6];
    const float* b0         = (const float*)d_in[7];
    const float* W1         = (const float*)d_in[8];
    const float* b1         = (const float*)d_in[9];
    float* out = (float*)d_out;

    const int n_neigh = in_sizes[2];
    const int n_rows  = n_neigh + 1;

    float* eg     = (float*)d_ws;
    float* z      = eg + (size_t)2 * n_rows * 64;
    float* zn     = z  + (size_t)2 * n_rows * 64;
    float* acc    = zn + (size_t)2 * n_rows * 64;
    int*   ticket = (int*)(acc + 12 * 64);

    const int grows = 2 * n_rows;
    const dim3 ggrid((grows + 15) / 16);          // 16 rows per 256-thr block
    const dim3 pgrid((n_rows + 3) / 4, 2);        // 1 row/wave
    const dim3 rgrid(ROUTE_BLOCKS, 2);
    const dim3 blk(256);

    hipLaunchKernelGGL(gather_kernel, ggrid, blk, 0, stream,
                       user, item, neigh_user, neigh_item, Gu, Gi,
                       (float4*)eg, acc, ticket, n_rows);
    // layer 0
    hipLaunchKernelGGL(proj_kernel, pgrid, blk, 0, stream,
                       W0, b0, eg, z, zn, acc, 0, n_rows);
    hipLaunchKernelGGL(route_kernel, rgrid, blk, 0, stream,
                       zn, acc, acc, ticket, out, 1, 0, 0, 0, n_neigh);
    hipLaunchKernelGGL(route_kernel, rgrid, blk, 0, stream,
                       zn, acc, acc, ticket, out, 0, 0, 1, 0, n_neigh);
    hipLaunchKernelGGL(route_kernel, rgrid, blk, 0, stream,
                       zn, acc, acc, ticket, out, 0, 1, 2, 0, n_neigh);
    // layer 1
    hipLaunchKernelGGL(proj_kernel, pgrid, blk, 0, stream,
                       W1, b1, eg, z, zn, acc, 1, n_rows);
    hipLaunchKernelGGL(route_kernel, rgrid, blk, 0, stream,
                       zn, acc, acc, ticket, out, 1, 0, 3, 0, n_neigh);
    hipLaunchKernelGGL(route_kernel, rgrid, blk, 0, stream,
                       zn, acc, acc, ticket, out, 0, 3, 4, 0, n_neigh);
    hipLaunchKernelGGL(route_kernel, rgrid, blk, 0, stream,
                       zn, acc, acc, ticket, out, 0, 4, 5, 1, n_neigh);
}